// Round 11
// baseline (982.120 us; speedup 1.0000x reference)
//
#include <hip/hip_runtime.h>

#define B_ 4
#define C_ 64
#define F_ 128
#define T_ 128
#define K_ 8
#define H_ 32
#define S_ 121   // T - K + 1
#define N_ 512   // B * F
#define G_ 128   // 4 * H
#define CK_ 512  // C * K

typedef __attribute__((ext_vector_type(8))) short short8;
typedef __attribute__((ext_vector_type(4))) float f32x4;
union FragU { uint4 u; short8 s; };

__device__ __forceinline__ unsigned int pk2(float a, float b){   // RNE f32->bf16 pair
  unsigned int ua = __float_as_uint(a); ua += 0x7fffu + ((ua>>16)&1u);
  unsigned int ub = __float_as_uint(b); ub += 0x7fffu + ((ub>>16)&1u);
  return (ua>>16) | (ub & 0xffff0000u);
}
__device__ __forceinline__ unsigned short bfu(float a){          // RNE f32->bf16
  unsigned int ua = __float_as_uint(a); ua += 0x7fffu + ((ua>>16)&1u);
  return (unsigned short)(ua>>16);
}

// gx slot permutation matched to MFMA C/D layout of the batched LSTM:
// lane (q,ln) consumes positions p = q*32 + t*4 + r as C[t][r]; p holds gate
// row (gate=t&3, j=q*8+(t>>2)*4+r).  g in [0,128): gate=g>>5, j=g&31.
__device__ __forceinline__ int newslot(int g){
  int j = g & 31;
  return (j >> 3)*32 + ((j >> 2) & 1)*16 + (g >> 5)*4 + (j & 3);
}

// ---------------------------------------------------------------- instance norm stats
__global__ __launch_bounds__(256) void k_norm(const float* __restrict__ x,
    const float* __restrict__ gamma, const float* __restrict__ beta,
    float* __restrict__ scale, float* __restrict__ shift){
  int bc = blockIdx.x;
  const float* p = x + (size_t)bc * (F_*T_);
  float s = 0.f, q = 0.f;
  for (int i = threadIdx.x; i < F_*T_; i += 256){ float v = p[i]; s += v; q += v*v; }
  #pragma unroll
  for (int o = 32; o; o >>= 1){ s += __shfl_down(s, o); q += __shfl_down(q, o); }
  __shared__ float ss[4], qq[4];
  int w = threadIdx.x >> 6;
  if ((threadIdx.x & 63) == 0){ ss[w] = s; qq[w] = q; }
  __syncthreads();
  if (threadIdx.x == 0){
    s = ss[0]+ss[1]+ss[2]+ss[3]; q = qq[0]+qq[1]+qq[2]+qq[3];
    float mu  = s / (float)(F_*T_);
    float var = q / (float)(F_*T_) - mu*mu;
    if (var < 0.f) var = 0.f;
    int c = bc & (C_-1);
    float sc = gamma[c] * rsqrtf(var + 1e-5f);
    scale[bc] = sc;
    shift[bc] = beta[c] - mu * sc;
  }
}

// ---------------------------------------------------------------- weight f32 -> bf16
__global__ __launch_bounds__(256) void k_wcvt(const float* __restrict__ a,
    unsigned short* __restrict__ o, int nel){
  int i = blockIdx.x*256 + threadIdx.x;
  if (i < nel) o[i] = bfu(a[i]);
}
// conv weights: bf16 + reverse k within each 8-block (absorbs conv flip into GEMM)
__global__ __launch_bounds__(256) void k_wrev(const float* __restrict__ a,
    unsigned short* __restrict__ o, int nel){
  int i = blockIdx.x*256 + threadIdx.x;
  if (i < nel){ int j = (i & ~7) | (7 - (i & 7)); o[i] = bfu(a[j]); }
}
// LSTM recurrent weights -> MFMA A-fragment layout, rows permuted so lane
// (q,ln) gets all 4 gates of its 8 hidden units.  wpre[l][d][t][m][32k] bf16.
__global__ __launch_bounds__(256) void k_wlstm(const float* __restrict__ whh0,
    const float* __restrict__ whh, unsigned short* __restrict__ wpre){
  int e = blockIdx.x*256 + threadIdx.x;
  if (e >= 4*2*8*16*32) return;
  int l = e >> 13, rem = e & 8191;
  int d = rem >> 12, t = (rem >> 9) & 7, m = (rem >> 5) & 15, k = rem & 31;
  int grow = (t & 3)*32 + (m >> 2)*8 + (t >> 2)*4 + (m & 3);
  float v = (l == 0) ? whh0[((size_t)d*128 + grow)*32 + k]
                     : whh[((size_t)((l-1)*2 + d)*128 + grow)*32 + k];
  wpre[e] = bfu(v);
}

// ---------------------------------------------------------------- layer-0 projection, MFMA bf16
__global__ __launch_bounds__(256) void k_gx0(const float* __restrict__ x,
    const float* __restrict__ scale, const float* __restrict__ shift,
    const unsigned short* __restrict__ wb0, const float* __restrict__ bi,
    const float* __restrict__ bh, unsigned short* __restrict__ gx){
  __shared__ __align__(16) char smem[63888];   // union: xsp (34,816 B) | gout (63,888 B)
  unsigned int (*xsp)[136] = (unsigned int (*)[136])smem;   // packed bf16 pairs (t,t+1)
  int n = blockIdx.x, b = n >> 7, f = n & 127;
  const float* xb = x + (size_t)b*C_*F_*T_ + (size_t)f*T_;
  for (int i = threadIdx.x; i < C_*136; i += 256){
    int c = i / 136, t = i - c*136;
    float sc = scale[b*C_+c], sh = shift[b*C_+c];
    float v0 = (t   < T_) ? xb[(size_t)c*F_*T_ + t  ]*sc + sh : 0.f;
    float v1 = (t+1 < T_) ? xb[(size_t)c*F_*T_ + t+1]*sc + sh : 0.f;
    xsp[c][t] = pk2(v0, v1);
  }
  __syncthreads();
  int lane = threadIdx.x & 63, wv = threadIdx.x >> 6;
  int ln = lane & 15, quad = lane >> 4;
  int g256[4]; f32x4 acc[8][4];
  #pragma unroll
  for (int gi = 0; gi < 4; ++gi){
    g256[gi] = (wv*4 + gi)*16 + ln;
    float bv = bi[g256[gi]] + bh[g256[gi]];
    #pragma unroll
    for (int st = 0; st < 8; ++st) acc[st][gi] = (f32x4){bv, bv, bv, bv};
  }
  uint4 bf0[4], bf1[4];
  unsigned int af0[8][4], af1[8][4];
  auto loadB = [&](uint4* bf, int kb){
    #pragma unroll
    for (int gi = 0; gi < 4; ++gi)
      bf[gi] = *(const uint4*)(wb0 + (size_t)g256[gi]*CK_ + kb*32 + quad*8);
  };
  auto loadA = [&](unsigned int (*af)[4], int kb){
    const unsigned int* base = &xsp[kb*4 + quad][ln];
    #pragma unroll
    for (int st = 0; st < 8; ++st){
      const unsigned int* rp = base + st*16;
      af[st][0] = rp[0]; af[st][1] = rp[2]; af[st][2] = rp[4]; af[st][3] = rp[6];
    }
  };
  auto domfma = [&](unsigned int (*af)[4], uint4* bf){
    #pragma unroll
    for (int st = 0; st < 8; ++st){
      FragU a; a.u.x = af[st][0]; a.u.y = af[st][1]; a.u.z = af[st][2]; a.u.w = af[st][3];
      #pragma unroll
      for (int gi = 0; gi < 4; ++gi){
        FragU bb2; bb2.u = bf[gi];
        acc[st][gi] = __builtin_amdgcn_mfma_f32_16x16x32_bf16(a.s, bb2.s, acc[st][gi], 0, 0, 0);
      }
    }
  };
  loadB(bf0, 0); loadA(af0, 0);
  #pragma unroll
  for (int kp = 0; kp < 8; ++kp){
    loadB(bf1, kp*2 + 1); loadA(af1, kp*2 + 1);
    domfma(af0, bf0);
    if (kp < 7){ loadB(bf0, kp*2 + 2); loadA(af0, kp*2 + 2); }
    domfma(af1, bf1);
  }
  // ---- coalesced epilogue via LDS transpose (cols in newslot order) ----
  __syncthreads();
  unsigned short* gout = (unsigned short*)smem; // [242][132]: row = d*121 + s
  #pragma unroll
  for (int st = 0; st < 8; ++st)
    #pragma unroll
    for (int gi = 0; gi < 4; ++gi){
      int d = g256[gi] >> 7, g = g256[gi] & 127;
      int col = newslot(g);
      #pragma unroll
      for (int r = 0; r < 4; ++r){
        int s = st*16 + quad*4 + r;
        if (s < S_) gout[(d*121 + s)*132 + col] = bfu(acc[st][gi][r]);
      }
    }
  __syncthreads();
  unsigned int* gxu = (unsigned int*)gx;
  const unsigned int* gu = (const unsigned int*)gout;   // row stride 66 dwords
  for (int i = threadIdx.x; i < 242*64; i += 256){
    int row = i >> 6, dc = i & 63;
    int d = (row >= 121) ? 1 : 0;
    int s = row - (d ? 121 : 0);
    gxu[((size_t)(d*N_ + n)*S_ + s)*64 + dc] = gu[row*66 + dc];
  }
}

// ---------------------------------------------------------------- layers 1..3 projection, MFMA bf16
// hin layout: [n][sb=st>>3][ci][4 dwords of st-pairs]; ci>=32 time-reversed (t=120-st)
__global__ __launch_bounds__(256) void k_gxl(const unsigned short* __restrict__ hin,
    const unsigned short* __restrict__ wlb, const float* __restrict__ bi,
    const float* __restrict__ bh, unsigned short* __restrict__ gx){
  __shared__ __align__(16) char smem[63888];   // raw (20,480) + hsp (16,896) | gout (63,888)
  unsigned int* raw = (unsigned int*)smem;                       // [sb][ci*5 + stw]
  unsigned int (*hsp)[132] = (unsigned int (*)[132])(smem + 20480);
  int n = blockIdx.x;
  const unsigned int* hu = (const unsigned int*)hin + (size_t)n*4096;
  for (int i = threadIdx.x; i < 4096; i += 256){
    int sb = i >> 8, ci = (i >> 2) & 63, stw = i & 3;
    raw[sb*320 + ci*5 + stw] = hu[i];
  }
  __syncthreads();
  auto rd16 = [&](int ci, int st)->unsigned int{
    unsigned int dd = raw[(st>>3)*320 + ci*5 + ((st&7)>>1)];
    return (st & 1) ? (dd >> 16) : (dd & 0xffffu);
  };
  for (int i = threadIdx.x; i < 32*128; i += 256){
    int srow = i >> 5, ip = i & 31;
    unsigned int v = 0;
    if (srow <= 120){
      int st = (ip < 16) ? srow : (120 - srow);
      v = rd16(2*ip, st) | (rd16(2*ip+1, st) << 16);
    }
    hsp[ip][srow] = v;
  }
  __syncthreads();
  int lane = threadIdx.x & 63, wv = threadIdx.x >> 6;
  int ln = lane & 15, quad = lane >> 4;
  int g256[4]; f32x4 acc[8][4];
  #pragma unroll
  for (int gi = 0; gi < 4; ++gi){
    g256[gi] = (wv*4 + gi)*16 + ln;
    float bv = bi[g256[gi]] + bh[g256[gi]];
    #pragma unroll
    for (int st = 0; st < 8; ++st) acc[st][gi] = (f32x4){bv, bv, bv, bv};
  }
  uint4 bf0[4], bf1[4];
  unsigned int af0[8][4], af1[8][4];
  auto loadB = [&](uint4* bf, int kb){
    #pragma unroll
    for (int gi = 0; gi < 4; ++gi)
      bf[gi] = *(const uint4*)(wlb + (size_t)g256[gi]*64 + kb*32 + quad*8);
  };
  auto loadA = [&](unsigned int (*af)[4], int kb){
    int ipb = kb*16 + quad*4;
    #pragma unroll
    for (int st = 0; st < 8; ++st){
      int srow = st*16 + ln;
      af[st][0] = hsp[ipb+0][srow]; af[st][1] = hsp[ipb+1][srow];
      af[st][2] = hsp[ipb+2][srow]; af[st][3] = hsp[ipb+3][srow];
    }
  };
  auto domfma = [&](unsigned int (*af)[4], uint4* bf){
    #pragma unroll
    for (int st = 0; st < 8; ++st){
      FragU a; a.u.x = af[st][0]; a.u.y = af[st][1]; a.u.z = af[st][2]; a.u.w = af[st][3];
      #pragma unroll
      for (int gi = 0; gi < 4; ++gi){
        FragU bb2; bb2.u = bf[gi];
        acc[st][gi] = __builtin_amdgcn_mfma_f32_16x16x32_bf16(a.s, bb2.s, acc[st][gi], 0, 0, 0);
      }
    }
  };
  loadB(bf0, 0); loadA(af0, 0);
  loadB(bf1, 1); loadA(af1, 1);
  domfma(af0, bf0);
  domfma(af1, bf1);
  // ---- coalesced epilogue via LDS transpose (cols in newslot order) ----
  __syncthreads();
  unsigned short* gout = (unsigned short*)smem;
  #pragma unroll
  for (int st = 0; st < 8; ++st)
    #pragma unroll
    for (int gi = 0; gi < 4; ++gi){
      int d = g256[gi] >> 7, g = g256[gi] & 127;
      int col = newslot(g);
      #pragma unroll
      for (int r = 0; r < 4; ++r){
        int s = st*16 + quad*4 + r;
        if (s < S_) gout[(d*121 + s)*132 + col] = bfu(acc[st][gi][r]);
      }
    }
  __syncthreads();
  unsigned int* gxu = (unsigned int*)gx;
  const unsigned int* gu = (const unsigned int*)gout;
  for (int i = threadIdx.x; i < 242*64; i += 256){
    int row = i >> 6, dc = i & 63;
    int d = (row >= 121) ? 1 : 0;
    int s = row - (d ? 121 : 0);
    gxu[((size_t)(d*N_ + n)*S_ + s)*64 + dc] = gu[row*66 + dc];
  }
}

// ---------------------------------------------------------------- LSTM: MFMA-batched, 16 chains/wave
// 8 mfma_16x16x32 per step: D[gate-tile][chain] = W_hh·h + gx(C operand).
// Row permutation (k_wlstm) puts all 4 gates of lane's 8 hidden units in-lane:
// cell update has ZERO cross-lane traffic; h lands in B-fragment layout.
__global__ __launch_bounds__(64)
__attribute__((amdgpu_waves_per_eu(1, 1)))
void k_lstm(const unsigned short* __restrict__ gx,
    const unsigned short* __restrict__ wpre,   // this layer: [d][t][m][32] bf16
    unsigned short* __restrict__ hout){
  int blk = blockIdx.x;            // 64 blocks x 64 threads
  int d = blk >> 5, nb = blk & 31;
  int lane = threadIdx.x;
  int ln = lane & 15, q = lane >> 4;
  int n = nb*16 + ln;              // this lane's chain (D column)
  FragU wf[8];
  const unsigned short* wb = wpre + (size_t)d*4096;
  #pragma unroll
  for (int t = 0; t < 8; ++t)
    wf[t].u = *(const uint4*)(wb + (t*16 + ln)*32 + q*8);

  const unsigned int* gxu = (const unsigned int*)gx;
  auto gptr = [&](int st)->const unsigned int*{
    int s = d ? (120 - st) : st;
    return gxu + ((size_t)(d*N_ + n)*S_ + s)*64 + q*16;
  };
  uint4 gb[2][4];
  #pragma unroll
  for (int r = 0; r < 4; ++r) gb[0][r] = *(const uint4*)(gptr(0) + 4*r);
  #pragma unroll
  for (int r = 0; r < 4; ++r) gb[1][r] = *(const uint4*)(gptr(1) + 4*r);

  float cst[8];
  #pragma unroll
  for (int jj = 0; jj < 8; ++jj) cst[jj] = 0.f;
  FragU bfr; bfr.u = (uint4){0u,0u,0u,0u};     // h(t=-1) = 0
  unsigned int hbuf[8][4], tmp16[8];
  int cibase = d*32 + q*8;

  auto step = [&](int st){
    int par = st & 1;
    const unsigned int* gd = (const unsigned int*)&gb[par][0];
    f32x4 acc[8];
    #pragma unroll
    for (int t = 0; t < 8; ++t){
      unsigned int d0 = gd[2*t], d1 = gd[2*t+1];
      acc[t][0] = __uint_as_float(d0 << 16);
      acc[t][1] = __uint_as_float(d0 & 0xffff0000u);
      acc[t][2] = __uint_as_float(d1 << 16);
      acc[t][3] = __uint_as_float(d1 & 0xffff0000u);
    }
    { // prefetch st+2 (clamped; clamp value never consumed)
      int pf = st + 2; if (pf > 120) pf = 120;
      const unsigned int* gp = gptr(pf);
      #pragma unroll
      for (int r = 0; r < 4; ++r) gb[par][r] = *(const uint4*)(gp + 4*r);
    }
    #pragma unroll
    for (int t = 0; t < 8; ++t)
      acc[t] = __builtin_amdgcn_mfma_f32_16x16x32_bf16(wf[t].s, bfr.s, acc[t], 0, 0, 0);
    float hf[8];
    #pragma unroll
    for (int jj = 0; jj < 8; ++jj){
      int b = jj >> 2, r = jj & 3;
      float iv = acc[4*b+0][r], fv = acc[4*b+1][r];
      float gv = acc[4*b+2][r], ov = acc[4*b+3][r];
      float si = 1.f/(1.f + __expf(-iv));
      float sf = 1.f/(1.f + __expf(-fv));
      float tg = 1.f - 2.f/(__expf(2.f*gv) + 1.f);
      float so = 1.f/(1.f + __expf(-ov));
      float cc = sf*cst[jj] + si*tg;
      cst[jj] = cc;
      float th = 1.f - 2.f/(__expf(2.f*cc) + 1.f);
      hf[jj] = so*th;
    }
    bfr.u.x = pk2(hf[0], hf[1]); bfr.u.y = pk2(hf[2], hf[3]);
    bfr.u.z = pk2(hf[4], hf[5]); bfr.u.w = pk2(hf[6], hf[7]);
    int stw = (st & 7) >> 1;
    if ((st & 1) == 0){
      #pragma unroll
      for (int jj = 0; jj < 8; ++jj) tmp16[jj] = (unsigned int)bfu(hf[jj]);
    } else {
      #pragma unroll
      for (int jj = 0; jj < 8; ++jj)
        hbuf[jj][stw] = tmp16[jj] | ((unsigned int)bfu(hf[jj]) << 16);
    }
  };

  for (int sb = 0; sb < 15; ++sb){
    #pragma unroll
    for (int u = 0; u < 8; ++u) step(sb*8 + u);
    unsigned short* hp = hout + ((size_t)(n*16 + sb)*64 + cibase)*8;
    #pragma unroll
    for (int jj = 0; jj < 8; ++jj)
      *(uint4*)(hp + jj*8) = (uint4){hbuf[jj][0], hbuf[jj][1], hbuf[jj][2], hbuf[jj][3]};
  }
  step(120);
  {
    unsigned short* hp = hout + ((size_t)(n*16 + 15)*64 + cibase)*8;
    #pragma unroll
    for (int jj = 0; jj < 8; ++jj)
      *(unsigned int*)(hp + jj*8) = tmp16[jj];   // st=120 in lo half; rest unread
  }
}

// ---------------------------------------------------------------- ConvTranspose via MFMA + bias + residual
// hin layout: [n][sb][ci][4 dwords st-pairs]; ci>=32 time-reversed (t = 120-st)
__global__ __launch_bounds__(256) void k_conv(const unsigned short* __restrict__ hin,
    const unsigned short* __restrict__ wA, const float* __restrict__ bct,
    const float* __restrict__ x, float* __restrict__ out){
  __shared__ unsigned int raw[5120];        // [sb][ci*5 + stw]
  __shared__ unsigned int hp2[64][144];     // overlapping bf16 pairs [ci][col], col=t'+8
  int n = blockIdx.x, b = n >> 7, f = n & 127;
  const unsigned int* hu = (const unsigned int*)hin + (size_t)n*4096;
  for (int i = threadIdx.x; i < 4096; i += 256){
    int sb = i >> 8, ci = (i >> 2) & 63, stw = i & 3;
    raw[sb*320 + ci*5 + stw] = hu[i];
  }
  __syncthreads();
  auto rd16 = [&](int ci, int st)->unsigned int{
    unsigned int dd = raw[(st>>3)*320 + ci*5 + ((st&7)>>1)];
    return (st & 1) ? (dd >> 16) : (dd & 0xffffu);
  };
  for (int it = threadIdx.x; it < 64*136; it += 256){
    int ci = it / 136, col = it - ci*136;
    int t0 = col - 8;
    unsigned int lo = 0, hi2 = 0;
    if (t0   >= 0 && t0   <= 120){ int st = (ci < 32) ? t0     : (120 - t0); lo  = rd16(ci, st); }
    if (t0+1 >= 0 && t0+1 <= 120){ int st = (ci < 32) ? (t0+1) : (119 - t0); hi2 = rd16(ci, st); }
    hp2[ci][col] = lo | (hi2 << 16);
  }
  __syncthreads();
  int lane = threadIdx.x & 63, wv = threadIdx.x >> 6;
  int ln = lane & 15, quad = lane >> 4;
  const unsigned short* wp = wA + (size_t)(wv*16 + ln)*512;
  f32x4 acc[8];
  #pragma unroll
  for (int nt = 0; nt < 8; ++nt) acc[nt] = (f32x4){0.f,0.f,0.f,0.f};
  for (int kb = 0; kb < 16; ++kb){
    FragU afr; afr.u = *(const uint4*)(wp + kb*32 + quad*8);
    int ci = kb*4 + quad;
    #pragma unroll
    for (int nt = 0; nt < 8; ++nt){
      FragU bfr;
      const unsigned int* rp = &hp2[ci][nt*16 + ln + 1];
      bfr.u.x = rp[0]; bfr.u.y = rp[2]; bfr.u.z = rp[4]; bfr.u.w = rp[6];
      acc[nt] = __builtin_amdgcn_mfma_f32_16x16x32_bf16(afr.s, bfr.s, acc[nt], 0, 0, 0);
    }
  }
  float bb[4];
  #pragma unroll
  for (int r = 0; r < 4; ++r) bb[r] = bct[wv*16 + quad*4 + r];
  #pragma unroll
  for (int nt = 0; nt < 8; ++nt)
    #pragma unroll
    for (int r = 0; r < 4; ++r){
      int co = wv*16 + quad*4 + r, t = nt*16 + ln;
      size_t idx = ((size_t)(b*64 + co)*128 + f)*128 + t;
      out[idx] = acc[nt][r] + bb[r] + x[idx];
    }
}

// ----------------------------------------------------------------
extern "C" void kernel_launch(void* const* d_in, const int* in_sizes, int n_in,
                              void* d_out, int out_size, void* d_ws, size_t ws_size,
                              hipStream_t stream){
  const float* x     = (const float*)d_in[0];
  const float* gamma = (const float*)d_in[1];
  const float* beta  = (const float*)d_in[2];
  const float* wih0  = (const float*)d_in[3];   // [2,128,512]
  const float* whh0  = (const float*)d_in[4];   // [2,128,32]
  const float* bih0  = (const float*)d_in[5];
  const float* bhh0  = (const float*)d_in[6];
  const float* wih   = (const float*)d_in[7];   // [3,2,128,64]
  const float* whh   = (const float*)d_in[8];   // [3,2,128,32]
  const float* bih   = (const float*)d_in[9];
  const float* bhh   = (const float*)d_in[10];
  const float* wct   = (const float*)d_in[11];  // [64,64,8]
  const float* bct   = (const float*)d_in[12];
  float* out = (float*)d_out;

  char* wsb = (char*)d_ws;
  float*          scale = (float*)(wsb);                       // 1 KB
  float*          shift = (float*)(wsb + 1024);                // 1 KB
  unsigned short* gx    = (unsigned short*)(wsb + 2048);       // 31,719,424 B
  unsigned short* hA    = (unsigned short*)(wsb + 31721472);   // 8,388,608 B
  unsigned short* hB    = (unsigned short*)(wsb + 40110080);   // 8,388,608 B
  unsigned short* wb0   = (unsigned short*)(wsb + 48498688);   // 262,144 B
  unsigned short* wlb   = (unsigned short*)(wsb + 48760832);   // 98,304 B
  unsigned short* wcv   = (unsigned short*)(wsb + 48859136);   // 65,536 B
  unsigned short* wpre  = (unsigned short*)(wsb + 48924672);   // 65,536 B (~49 MB total)

  k_norm <<<256, 256, 0, stream>>>(x, gamma, beta, scale, shift);
  k_wcvt <<<512, 256, 0, stream>>>(wih0, wb0, 2*G_*CK_);
  k_wcvt <<<192, 256, 0, stream>>>(wih,  wlb, 3*2*G_*64);
  k_wrev <<<128, 256, 0, stream>>>(wct,  wcv, 64*512);
  k_wlstm<<<128, 256, 0, stream>>>(whh0, whh, wpre);
  k_gx0  <<<512, 256, 0, stream>>>(x, scale, shift, wb0, bih0, bhh0, gx);
  k_lstm <<<64, 64, 0, stream>>>(gx, wpre, hA);
  unsigned short* hp = hA; unsigned short* hn = hB;
  for (int l = 0; l < 3; ++l){
    k_gxl <<<512, 256, 0, stream>>>(hp, wlb + (size_t)l*2*G_*64,
                                    bih + (size_t)l*2*G_, bhh + (size_t)l*2*G_, gx);
    k_lstm<<<64, 64, 0, stream>>>(gx, wpre + (size_t)(l+1)*8192, hn);
    unsigned short* tmp = hp; hp = hn; hn = tmp;
  }
  k_conv<<<512, 256, 0, stream>>>(hp, wcv, bct, x, out);
}

// Round 12
// 581.146 us; speedup vs baseline: 1.6900x; 1.6900x over previous
//
#include <hip/hip_runtime.h>

#define B_ 4
#define C_ 64
#define F_ 128
#define T_ 128
#define K_ 8
#define H_ 32
#define S_ 121   // T - K + 1
#define N_ 512   // B * F
#define G_ 128   // 4 * H
#define CK_ 512  // C * K

typedef __attribute__((ext_vector_type(8))) short short8;
typedef __attribute__((ext_vector_type(4))) float f32x4;
union FragU { uint4 u; short8 s; };

__device__ __forceinline__ unsigned int pk2(float a, float b){   // RNE f32->bf16 pair
  unsigned int ua = __float_as_uint(a); ua += 0x7fffu + ((ua>>16)&1u);
  unsigned int ub = __float_as_uint(b); ub += 0x7fffu + ((ub>>16)&1u);
  return (ua>>16) | (ub & 0xffff0000u);
}
__device__ __forceinline__ unsigned short bfu(float a){          // RNE f32->bf16
  unsigned int ua = __float_as_uint(a); ua += 0x7fffu + ((ua>>16)&1u);
  return (unsigned short)(ua>>16);
}
__device__ __forceinline__ float ubf(unsigned short v){
  return __uint_as_float(((unsigned int)v) << 16);
}

// gx gate-pair interleaved slot: lane l of k_lstm reads one dword = (row l | row l+64 <<16)
__device__ __forceinline__ int gslot(int g){ return ((g & 63) << 1) | (g >> 6); }

// ---------------------------------------------------------------- instance norm stats
__global__ __launch_bounds__(256) void k_norm(const float* __restrict__ x,
    const float* __restrict__ gamma, const float* __restrict__ beta,
    float* __restrict__ scale, float* __restrict__ shift){
  int bc = blockIdx.x;
  const float* p = x + (size_t)bc * (F_*T_);
  float s = 0.f, q = 0.f;
  for (int i = threadIdx.x; i < F_*T_; i += 256){ float v = p[i]; s += v; q += v*v; }
  #pragma unroll
  for (int o = 32; o; o >>= 1){ s += __shfl_down(s, o); q += __shfl_down(q, o); }
  __shared__ float ss[4], qq[4];
  int w = threadIdx.x >> 6;
  if ((threadIdx.x & 63) == 0){ ss[w] = s; qq[w] = q; }
  __syncthreads();
  if (threadIdx.x == 0){
    s = ss[0]+ss[1]+ss[2]+ss[3]; q = qq[0]+qq[1]+qq[2]+qq[3];
    float mu  = s / (float)(F_*T_);
    float var = q / (float)(F_*T_) - mu*mu;
    if (var < 0.f) var = 0.f;
    int c = bc & (C_-1);
    float sc = gamma[c] * rsqrtf(var + 1e-5f);
    scale[bc] = sc;
    shift[bc] = beta[c] - mu * sc;
  }
}

// ---------------------------------------------------------------- weight f32 -> bf16
__global__ __launch_bounds__(256) void k_wcvt(const float* __restrict__ a,
    unsigned short* __restrict__ o, int nel){
  int i = blockIdx.x*256 + threadIdx.x;
  if (i < nel) o[i] = bfu(a[i]);
}
// conv weights: bf16 + reverse k within each 8-block (absorbs conv flip into GEMM)
__global__ __launch_bounds__(256) void k_wrev(const float* __restrict__ a,
    unsigned short* __restrict__ o, int nel){
  int i = blockIdx.x*256 + threadIdx.x;
  if (i < nel){ int j = (i & ~7) | (7 - (i & 7)); o[i] = bfu(a[j]); }
}

// ---------------------------------------------------------------- layer-0 projection, MFMA bf16
__global__ __launch_bounds__(256) void k_gx0(const float* __restrict__ x,
    const float* __restrict__ scale, const float* __restrict__ shift,
    const unsigned short* __restrict__ wb0, const float* __restrict__ bi,
    const float* __restrict__ bh, unsigned short* __restrict__ gx){
  __shared__ __align__(16) char smem[63888];   // union: xsp (34,816 B) | gout (63,888 B)
  unsigned int (*xsp)[136] = (unsigned int (*)[136])smem;   // packed bf16 pairs (t,t+1)
  int n = blockIdx.x, b = n >> 7, f = n & 127;
  const float* xb = x + (size_t)b*C_*F_*T_ + (size_t)f*T_;
  for (int i = threadIdx.x; i < C_*136; i += 256){
    int c = i / 136, t = i - c*136;
    float sc = scale[b*C_+c], sh = shift[b*C_+c];
    float v0 = (t   < T_) ? xb[(size_t)c*F_*T_ + t  ]*sc + sh : 0.f;
    float v1 = (t+1 < T_) ? xb[(size_t)c*F_*T_ + t+1]*sc + sh : 0.f;
    xsp[c][t] = pk2(v0, v1);
  }
  __syncthreads();
  int lane = threadIdx.x & 63, wv = threadIdx.x >> 6;
  int ln = lane & 15, quad = lane >> 4;
  int g256[4]; f32x4 acc[8][4];
  #pragma unroll
  for (int gi = 0; gi < 4; ++gi){
    g256[gi] = (wv*4 + gi)*16 + ln;
    float bv = bi[g256[gi]] + bh[g256[gi]];
    #pragma unroll
    for (int st = 0; st < 8; ++st) acc[st][gi] = (f32x4){bv, bv, bv, bv};
  }
  uint4 bf0[4], bf1[4];
  unsigned int af0[8][4], af1[8][4];
  auto loadB = [&](uint4* bf, int kb){
    #pragma unroll
    for (int gi = 0; gi < 4; ++gi)
      bf[gi] = *(const uint4*)(wb0 + (size_t)g256[gi]*CK_ + kb*32 + quad*8);
  };
  auto loadA = [&](unsigned int (*af)[4], int kb){
    const unsigned int* base = &xsp[kb*4 + quad][ln];
    #pragma unroll
    for (int st = 0; st < 8; ++st){
      const unsigned int* rp = base + st*16;
      af[st][0] = rp[0]; af[st][1] = rp[2]; af[st][2] = rp[4]; af[st][3] = rp[6];
    }
  };
  auto domfma = [&](unsigned int (*af)[4], uint4* bf){
    #pragma unroll
    for (int st = 0; st < 8; ++st){
      FragU a; a.u.x = af[st][0]; a.u.y = af[st][1]; a.u.z = af[st][2]; a.u.w = af[st][3];
      #pragma unroll
      for (int gi = 0; gi < 4; ++gi){
        FragU bb2; bb2.u = bf[gi];
        acc[st][gi] = __builtin_amdgcn_mfma_f32_16x16x32_bf16(a.s, bb2.s, acc[st][gi], 0, 0, 0);
      }
    }
  };
  loadB(bf0, 0); loadA(af0, 0);
  #pragma unroll
  for (int kp = 0; kp < 8; ++kp){
    loadB(bf1, kp*2 + 1); loadA(af1, kp*2 + 1);
    domfma(af0, bf0);
    if (kp < 7){ loadB(bf0, kp*2 + 2); loadA(af0, kp*2 + 2); }
    domfma(af1, bf1);
  }
  // ---- coalesced epilogue via LDS transpose ----
  __syncthreads();                              // all xsp reads done; reuse as gout
  unsigned short* gout = (unsigned short*)smem; // [242][132]: row = d*121 + s
  #pragma unroll
  for (int st = 0; st < 8; ++st)
    #pragma unroll
    for (int gi = 0; gi < 4; ++gi){
      int d = g256[gi] >> 7, g = g256[gi] & 127;
      int col = gslot(g);
      #pragma unroll
      for (int r = 0; r < 4; ++r){
        int s = st*16 + quad*4 + r;
        if (s < S_) gout[(d*121 + s)*132 + col] = bfu(acc[st][gi][r]);
      }
    }
  __syncthreads();
  unsigned int* gxu = (unsigned int*)gx;
  const unsigned int* gu = (const unsigned int*)gout;   // row stride 66 dwords
  for (int i = threadIdx.x; i < 242*64; i += 256){
    int row = i >> 6, dc = i & 63;
    int d = (row >= 121) ? 1 : 0;
    int s = row - (d ? 121 : 0);
    gxu[((size_t)(d*N_ + n)*S_ + s)*64 + dc] = gu[row*66 + dc];
  }
}

// ---------------------------------------------------------------- layers 1..3 projection, MFMA bf16
// hin layout: [n][ci][128] bf16, st-indexed (d=1 half time-reversed: t = 120 - st)
__global__ __launch_bounds__(256) void k_gxl(const unsigned short* __restrict__ hin,
    const unsigned short* __restrict__ wlb, const float* __restrict__ bi,
    const float* __restrict__ bh, unsigned short* __restrict__ gx){
  __shared__ __align__(16) char smem[63888];   // union: hrawL+hsp (33,536 B) | gout (63,888 B)
  unsigned int (*hrawL)[65]  = (unsigned int (*)[65])smem;           // raw rows [ci][64 dwords]
  unsigned int (*hsp)[132]   = (unsigned int (*)[132])(smem + 16640);// [ci_pair][s]
  int n = blockIdx.x;
  const unsigned int* hu = (const unsigned int*)hin + (size_t)n*64*64;
  for (int i = threadIdx.x; i < 64*64; i += 256){
    int ci = i >> 6, k = i & 63;
    hrawL[ci][k] = hu[ci*64 + k];
  }
  __syncthreads();
  const unsigned short* rawu = (const unsigned short*)&hrawL[0][0];  // row stride 130 u16
  for (int i = threadIdx.x; i < 32*128; i += 256){
    int srow = i >> 5, ip = i & 31;
    unsigned int v = 0;
    if (srow <= 120){
      int st = (ip < 16) ? srow : (120 - srow);
      v = (unsigned int)rawu[(2*ip)*130 + st] | ((unsigned int)rawu[(2*ip+1)*130 + st] << 16);
    }
    hsp[ip][srow] = v;
  }
  __syncthreads();
  int lane = threadIdx.x & 63, wv = threadIdx.x >> 6;
  int ln = lane & 15, quad = lane >> 4;
  int g256[4]; f32x4 acc[8][4];
  #pragma unroll
  for (int gi = 0; gi < 4; ++gi){
    g256[gi] = (wv*4 + gi)*16 + ln;
    float bv = bi[g256[gi]] + bh[g256[gi]];
    #pragma unroll
    for (int st = 0; st < 8; ++st) acc[st][gi] = (f32x4){bv, bv, bv, bv};
  }
  uint4 bf0[4], bf1[4];
  unsigned int af0[8][4], af1[8][4];
  auto loadB = [&](uint4* bf, int kb){
    #pragma unroll
    for (int gi = 0; gi < 4; ++gi)
      bf[gi] = *(const uint4*)(wlb + (size_t)g256[gi]*64 + kb*32 + quad*8);
  };
  auto loadA = [&](unsigned int (*af)[4], int kb){
    int ipb = kb*16 + quad*4;
    #pragma unroll
    for (int st = 0; st < 8; ++st){
      int srow = st*16 + ln;
      af[st][0] = hsp[ipb+0][srow]; af[st][1] = hsp[ipb+1][srow];
      af[st][2] = hsp[ipb+2][srow]; af[st][3] = hsp[ipb+3][srow];
    }
  };
  auto domfma = [&](unsigned int (*af)[4], uint4* bf){
    #pragma unroll
    for (int st = 0; st < 8; ++st){
      FragU a; a.u.x = af[st][0]; a.u.y = af[st][1]; a.u.z = af[st][2]; a.u.w = af[st][3];
      #pragma unroll
      for (int gi = 0; gi < 4; ++gi){
        FragU bb2; bb2.u = bf[gi];
        acc[st][gi] = __builtin_amdgcn_mfma_f32_16x16x32_bf16(a.s, bb2.s, acc[st][gi], 0, 0, 0);
      }
    }
  };
  loadB(bf0, 0); loadA(af0, 0);
  loadB(bf1, 1); loadA(af1, 1);
  domfma(af0, bf0);
  domfma(af1, bf1);
  // ---- coalesced epilogue via LDS transpose ----
  __syncthreads();
  unsigned short* gout = (unsigned short*)smem; // [242][132]: row = d*121 + s
  #pragma unroll
  for (int st = 0; st < 8; ++st)
    #pragma unroll
    for (int gi = 0; gi < 4; ++gi){
      int d = g256[gi] >> 7, g = g256[gi] & 127;
      int col = gslot(g);
      #pragma unroll
      for (int r = 0; r < 4; ++r){
        int s = st*16 + quad*4 + r;
        if (s < S_) gout[(d*121 + s)*132 + col] = bfu(acc[st][gi][r]);
      }
    }
  __syncthreads();
  unsigned int* gxu = (unsigned int*)gx;
  const unsigned int* gu = (const unsigned int*)gout;   // row stride 66 dwords
  for (int i = threadIdx.x; i < 242*64; i += 256){
    int row = i >> 6, dc = i & 63;
    int d = (row >= 121) ? 1 : 0;
    int s = row - (d ? 121 : 0);
    gxu[((size_t)(d*N_ + n)*S_ + s)*64 + dc] = gu[row*66 + dc];
  }
}

// ---------------------------------------------------------------- LSTM: TWO chains per wave
// Round-12: dual-chain ILP. Same direction -> shared w1/w2 registers; the two
// independent recurrences interleave and hide each other's trans/shuffle/readlane
// latency (R10 showed 37% VALUBusy = 63% un-hidden stall with one chain/wave).
// Grouped double-buffered gx loads + batched h stores per chain (R8 structure).
__global__ __launch_bounds__(64)
__attribute__((amdgpu_waves_per_eu(1, 1)))
void k_lstm(const unsigned short* __restrict__ gx,
    const float* __restrict__ whh, unsigned short* __restrict__ hout){
  int blk = blockIdx.x;              // 512 blocks: d = blk>>8, pair = blk&255
  int d = blk >> 8, m = blk & 255;
  int n0 = 2*m, n1 = 2*m + 1;
  int lane = threadIdx.x;
  int j = lane & 31, hi = lane >> 5;
  float w1[32], w2[32];
  const float* wr1 = whh + (size_t)(d*G_ + lane)*H_;
  const float* wr2 = whh + (size_t)(d*G_ + lane + 64)*H_;
  #pragma unroll
  for (int q = 0; q < 8; ++q){
    float4 aa = *(const float4*)(wr1 + q*4);
    float4 bb = *(const float4*)(wr2 + q*4);
    w1[q*4+0]=aa.x; w1[q*4+1]=aa.y; w1[q*4+2]=aa.z; w1[q*4+3]=aa.w;
    w2[q*4+0]=bb.x; w2[q*4+1]=bb.y; w2[q*4+2]=bb.z; w2[q*4+3]=bb.w;
  }
  #pragma unroll
  for (int k = 0; k < 32; ++k){               // pin weights (no sink/remat)
    asm volatile("" : "+v"(w1[k]));
    asm volatile("" : "+v"(w2[k]));
  }
  const unsigned int* gxu = (const unsigned int*)gx;
  ptrdiff_t stride = d ? -64 : 64;
  const unsigned int* p0 = gxu + ((size_t)(d*N_ + n0)*S_ + (d ? (S_-1) : 0))*64 + lane;
  const unsigned int* p1 = gxu + ((size_t)(d*N_ + n1)*S_ + (d ? (S_-1) : 0))*64 + lane;
  unsigned short* hop0 = hout + ((size_t)n0*64 + d*32 + j)*128;   // st-indexed rows
  unsigned short* hop1 = hout + ((size_t)n1*64 + d*32 + j)*128;

  float hv0 = 0.f, c0 = 0.f, hv1 = 0.f, c1 = 0.f;
  unsigned int hg0[4], hg1[4];
  auto rl = [&](float v, int k)->float{
    return __uint_as_float(__builtin_amdgcn_readlane(__float_as_uint(v), k));
  };
  auto step2 = [&](unsigned int x0, unsigned int x1, int u){
    float sA1 = __uint_as_float(x0 << 16),          sA2 = 0.f;
    float sA3 = __uint_as_float(x0 & 0xffff0000u),  sA4 = 0.f;
    float sB1 = __uint_as_float(x1 << 16),          sB2 = 0.f;
    float sB3 = __uint_as_float(x1 & 0xffff0000u),  sB4 = 0.f;
    #pragma unroll
    for (int k = 0; k < 32; k += 2){
      float hA0 = rl(hv0, k), hA1 = rl(hv0, k+1);
      float hB0 = rl(hv1, k), hB1 = rl(hv1, k+1);
      sA1 += hA0*w1[k]; sA2 += hA1*w1[k+1];
      sA3 += hA0*w2[k]; sA4 += hA1*w2[k+1];
      sB1 += hB0*w1[k]; sB2 += hB1*w1[k+1];
      sB3 += hB0*w2[k]; sB4 += hB1*w2[k+1];
    }
    float accA1 = sA1 + sA2, accA2 = sA3 + sA4;
    float accB1 = sB1 + sB2, accB2 = sB3 + sB4;
    // chain A nonlinearities
    float a1A = 1.f/(1.f + __expf(-accA1));
    float x2A = hi ? accA2 : 2.f*accA2;
    float ttA = 1.f/(1.f + __expf(-x2A));
    float a2A = hi ? ttA : 2.f*ttA - 1.f;
    // chain B nonlinearities (independent: overlaps A's latency)
    float a1B = 1.f/(1.f + __expf(-accB1));
    float x2B = hi ? accB2 : 2.f*accB2;
    float ttB = 1.f/(1.f + __expf(-x2B));
    float a2B = hi ? ttB : 2.f*ttB - 1.f;
    float b1A = __shfl_xor(a1A, 32), b2A = __shfl_xor(a2A, 32);
    float b1B = __shfl_xor(a1B, 32), b2B = __shfl_xor(a2B, 32);
    {
      float i_ = hi ? b1A : a1A, f_ = hi ? a1A : b1A;
      float g_ = hi ? b2A : a2A, o_ = hi ? a2A : b2A;
      c0 = f_*c0 + i_*g_;
      float tc = 1.f/(1.f + __expf(-2.f*c0));
      hv0 = o_*(2.f*tc - 1.f);
    }
    {
      float i_ = hi ? b1B : a1B, f_ = hi ? a1B : b1B;
      float g_ = hi ? b2B : a2B, o_ = hi ? a2B : b2B;
      c1 = f_*c1 + i_*g_;
      float tc = 1.f/(1.f + __expf(-2.f*c1));
      hv1 = o_*(2.f*tc - 1.f);
    }
    unsigned int hb0 = (unsigned int)bfu(hv0);
    unsigned int hb1 = (unsigned int)bfu(hv1);
    if ((u & 1) == 0){ hg0[u >> 1] = hb0;          hg1[u >> 1] = hb1; }
    else             { hg0[u >> 1] |= hb0 << 16;   hg1[u >> 1] |= hb1 << 16; }
  };

  unsigned int bA0[8], bB0[8], bA1[8], bB1[8];
  #pragma unroll
  for (int u = 0; u < 8; ++u){ bA0[u] = p0[stride*u]; bA1[u] = p1[stride*u]; }

  for (int gg = 0; gg < 7; ++gg){            // groups 0..13 (steps 0..111)
    int g0 = gg*2;
    #pragma unroll
    for (int u = 0; u < 8; ++u){ bB0[u] = p0[stride*(8*(g0+1) + u)]; bB1[u] = p1[stride*(8*(g0+1) + u)]; }
    #pragma unroll
    for (int u = 0; u < 8; ++u) step2(bA0[u], bA1[u], u);
    if (!hi){
      *(uint4*)(hop0 + 8*g0) = (uint4){hg0[0], hg0[1], hg0[2], hg0[3]};
      *(uint4*)(hop1 + 8*g0) = (uint4){hg1[0], hg1[1], hg1[2], hg1[3]};
    }
    #pragma unroll
    for (int u = 0; u < 8; ++u){ bA0[u] = p0[stride*(8*(g0+2) + u)]; bA1[u] = p1[stride*(8*(g0+2) + u)]; }
    #pragma unroll
    for (int u = 0; u < 8; ++u) step2(bB0[u], bB1[u], u);
    if (!hi){
      *(uint4*)(hop0 + 8*(g0+1)) = (uint4){hg0[0], hg0[1], hg0[2], hg0[3]};
      *(uint4*)(hop1 + 8*(g0+1)) = (uint4){hg1[0], hg1[1], hg1[2], hg1[3]};
    }
  }
  // group 14 (steps 112..119), prefetch st=120
  bB0[0] = p0[stride*120]; bB1[0] = p1[stride*120];
  #pragma unroll
  for (int u = 0; u < 8; ++u) step2(bA0[u], bA1[u], u);
  if (!hi){
    *(uint4*)(hop0 + 112) = (uint4){hg0[0], hg0[1], hg0[2], hg0[3]};
    *(uint4*)(hop1 + 112) = (uint4){hg1[0], hg1[1], hg1[2], hg1[3]};
  }
  // step 120
  step2(bB0[0], bB1[0], 0);
  if (!hi){
    hop0[120] = (unsigned short)(hg0[0] & 0xffffu);
    hop1[120] = (unsigned short)(hg1[0] & 0xffffu);
  }
}

// ---------------------------------------------------------------- ConvTranspose via MFMA + bias + residual
// hin layout: [n][ci][128] bf16 st-indexed (ci>=32 time-reversed: t = 120 - st)
__global__ __launch_bounds__(256) void k_conv(const unsigned short* __restrict__ hin,
    const unsigned short* __restrict__ wA, const float* __restrict__ bct,
    const float* __restrict__ x, float* __restrict__ out){
  __shared__ unsigned int hrawL[64][65];    // raw rows [ci][64 dwords]
  __shared__ unsigned int hp2[64][144];     // overlapping bf16 pairs [ci][col], col=t'+8
  int n = blockIdx.x, b = n >> 7, f = n & 127;
  const unsigned int* hu = (const unsigned int*)hin + (size_t)n*64*64;
  for (int i = threadIdx.x; i < 64*64; i += 256){
    int ci = i >> 6, k = i & 63;
    hrawL[ci][k] = hu[ci*64 + k];
  }
  __syncthreads();
  const unsigned short* rawu = (const unsigned short*)&hrawL[0][0];  // row stride 130 u16
  for (int it = threadIdx.x; it < 64*136; it += 256){
    int ci = it / 136, col = it - ci*136;
    int t0 = col - 8;
    int i0 = (ci < 32) ? t0 : (120 - t0);
    int i1 = (ci < 32) ? (t0+1) : (119 - t0);
    unsigned int lo  = (t0   >= 0 && t0   <= 120) ? rawu[ci*130 + i0] : 0u;
    unsigned int hi2 = (t0+1 >= 0 && t0+1 <= 120) ? rawu[ci*130 + i1] : 0u;
    hp2[ci][col] = lo | (hi2 << 16);
  }
  __syncthreads();
  int lane = threadIdx.x & 63, wv = threadIdx.x >> 6;
  int ln = lane & 15, quad = lane >> 4;
  const unsigned short* wp = wA + (size_t)(wv*16 + ln)*512;
  f32x4 acc[8];
  #pragma unroll
  for (int nt = 0; nt < 8; ++nt) acc[nt] = (f32x4){0.f,0.f,0.f,0.f};
  for (int kb = 0; kb < 16; ++kb){
    FragU afr; afr.u = *(const uint4*)(wp + kb*32 + quad*8);
    int ci = kb*4 + quad;
    #pragma unroll
    for (int nt = 0; nt < 8; ++nt){
      FragU bfr;
      const unsigned int* rp = &hp2[ci][nt*16 + ln + 1];
      bfr.u.x = rp[0]; bfr.u.y = rp[2]; bfr.u.z = rp[4]; bfr.u.w = rp[6];
      acc[nt] = __builtin_amdgcn_mfma_f32_16x16x32_bf16(afr.s, bfr.s, acc[nt], 0, 0, 0);
    }
  }
  float bb[4];
  #pragma unroll
  for (int r = 0; r < 4; ++r) bb[r] = bct[wv*16 + quad*4 + r];
  #pragma unroll
  for (int nt = 0; nt < 8; ++nt)
    #pragma unroll
    for (int r = 0; r < 4; ++r){
      int co = wv*16 + quad*4 + r, t = nt*16 + ln;
      size_t idx = ((size_t)(b*64 + co)*128 + f)*128 + t;
      out[idx] = acc[nt][r] + bb[r] + x[idx];
    }
}

// ----------------------------------------------------------------
extern "C" void kernel_launch(void* const* d_in, const int* in_sizes, int n_in,
                              void* d_out, int out_size, void* d_ws, size_t ws_size,
                              hipStream_t stream){
  const float* x     = (const float*)d_in[0];
  const float* gamma = (const float*)d_in[1];
  const float* beta  = (const float*)d_in[2];
  const float* wih0  = (const float*)d_in[3];   // [2,128,512]
  const float* whh0  = (const float*)d_in[4];   // [2,128,32]
  const float* bih0  = (const float*)d_in[5];
  const float* bhh0  = (const float*)d_in[6];
  const float* wih   = (const float*)d_in[7];   // [3,2,128,64]
  const float* whh   = (const float*)d_in[8];   // [3,2,128,32]
  const float* bih   = (const float*)d_in[9];
  const float* bhh   = (const float*)d_in[10];
  const float* wct   = (const float*)d_in[11];  // [64,64,8]
  const float* bct   = (const float*)d_in[12];
  float* out = (float*)d_out;

  char* wsb = (char*)d_ws;
  float*          scale = (float*)(wsb);                       // 1 KB
  float*          shift = (float*)(wsb + 1024);                // 1 KB
  unsigned short* gx    = (unsigned short*)(wsb + 2048);       // 31,719,424 B
  unsigned short* hA    = (unsigned short*)(wsb + 31721472);   // 512*64*128*2 = 8,388,608 B
  unsigned short* hB    = (unsigned short*)(wsb + 40110080);   // 8,388,608 B
  unsigned short* wb0   = (unsigned short*)(wsb + 48498688);   // 262,144 B
  unsigned short* wlb   = (unsigned short*)(wsb + 48760832);   // 98,304 B
  unsigned short* wcv   = (unsigned short*)(wsb + 48859136);   // 65,536 B (~48.9 MB total)

  k_norm<<<256, 256, 0, stream>>>(x, gamma, beta, scale, shift);
  k_wcvt<<<512, 256, 0, stream>>>(wih0, wb0, 2*G_*CK_);
  k_wcvt<<<192, 256, 0, stream>>>(wih,  wlb, 3*2*G_*64);
  k_wrev<<<128, 256, 0, stream>>>(wct,  wcv, 64*512);
  k_gx0 <<<512, 256, 0, stream>>>(x, scale, shift, wb0, bih0, bhh0, gx);
  k_lstm<<<512, 64, 0, stream>>>(gx, whh0, hA);
  unsigned short* hp = hA; unsigned short* hn = hB;
  for (int l = 0; l < 3; ++l){
    k_gxl <<<512, 256, 0, stream>>>(hp, wlb + (size_t)l*2*G_*64,
                                    bih + (size_t)l*2*G_, bhh + (size_t)l*2*G_, gx);
    k_lstm<<<512, 64, 0, stream>>>(gx, whh + (size_t)l*2*G_*H_, hn);
    unsigned short* tmp = hp; hp = hn; hn = tmp;
  }
  k_conv<<<512, 256, 0, stream>>>(hp, wcv, bct, x, out);
}